// Round 4
// baseline (221.655 us; speedup 1.0000x reference)
//
#include <hip/hip_runtime.h>
#include <hip/hip_bf16.h>

#define D_MODEL 1024
#define NH 16
#define HD 64
#define S_LEN 2048
#define NB 2
#define M_TOT 4096
#define N3 3072

typedef __attribute__((ext_vector_type(8))) short bf16x8;
typedef __attribute__((ext_vector_type(4))) float f32x4;
typedef __attribute__((ext_vector_type(4))) unsigned short u16x4;

__device__ __forceinline__ unsigned short f2bf(float f) {
    unsigned int u = __float_as_uint(f);
    u += 0x7fffu + ((u >> 16) & 1u);
    return (unsigned short)(u >> 16);
}

#define GLOAD_LDS(gp, lp)                                                      \
    __builtin_amdgcn_global_load_lds(                                          \
        (const __attribute__((address_space(1))) void*)(gp),                   \
        (__attribute__((address_space(3))) void*)(lp), 16, 0, 0)

// ---------------------------------------------------------------- fused casts
__global__ __launch_bounds__(256) void cast_both(
    const float* __restrict__ x, const float* __restrict__ W,
    unsigned short* __restrict__ xb, unsigned short* __restrict__ Wb) {
    const int nx = M_TOT * D_MODEL / 4;
    const int nw = N3 * D_MODEL / 4;
    int i = blockIdx.x * 256 + threadIdx.x;
    const float* src;
    unsigned short* dst;
    int j;
    if (i < nx) { src = x; dst = xb; j = i; }
    else { j = i - nx; if (j >= nw) return; src = W; dst = Wb; }
    float4 v = reinterpret_cast<const float4*>(src)[j];
    u16x4 o;
    o.x = f2bf(v.x); o.y = f2bf(v.y); o.z = f2bf(v.z); o.w = f2bf(v.w);
    reinterpret_cast<u16x4*>(dst)[j] = o;
}

// ---------------------------------------------------------------- QKV GEMM (m97 structure, unchanged)
#define BM 128
#define BN 128
#define BK 64

__global__ __launch_bounds__(256) void qkv_gemm(
    const unsigned short* __restrict__ A, const unsigned short* __restrict__ B,
    const float* __restrict__ bias, unsigned short* __restrict__ Z) {
    __shared__ unsigned short As[BM * BK];
    __shared__ unsigned short Bs[BN * BK];

    const int t = threadIdx.x;
    const int lane = t & 63;
    const int wid = t >> 6;
    const int wr = wid >> 1, wc = wid & 1;
    const int bm = blockIdx.y, bn = blockIdx.x;
    const int lr = lane & 15;
    const int lg = lane >> 4;
    const int srow = lane >> 3;
    const int sslot = lane & 7;

    f32x4 acc[4][4] = {};

    for (int k0 = 0; k0 < 1024; k0 += BK) {
        __syncthreads();
#pragma unroll
        for (int p = 0; p < 4; ++p) {
            int rb = wid * 32 + p * 8;
            int row = rb + srow;
            int seg = sslot ^ (row & 7);
            GLOAD_LDS(&A[(size_t)(bm * BM + row) * 1024 + k0 + seg * 8],
                      &As[rb * BK]);
            GLOAD_LDS(&B[(size_t)(bn * BN + row) * 1024 + k0 + seg * 8],
                      &Bs[rb * BK]);
        }
        __syncthreads();
#pragma unroll
        for (int ks = 0; ks < 2; ++ks) {
            bf16x8 af[4], bfr[4];
#pragma unroll
            for (int m = 0; m < 4; ++m) {
                int row = wr * 64 + m * 16 + lr;
                int slot = (ks * 4 + lg) ^ (row & 7);
                af[m] = *reinterpret_cast<const bf16x8*>(&As[row * BK + slot * 8]);
            }
#pragma unroll
            for (int n = 0; n < 4; ++n) {
                int row = wc * 64 + n * 16 + lr;
                int slot = (ks * 4 + lg) ^ (row & 7);
                bfr[n] = *reinterpret_cast<const bf16x8*>(&Bs[row * BK + slot * 8]);
            }
#pragma unroll
            for (int m = 0; m < 4; ++m)
#pragma unroll
                for (int n = 0; n < 4; ++n)
                    acc[m][n] = __builtin_amdgcn_mfma_f32_16x16x32_bf16(
                        af[m], bfr[n], acc[m][n], 0, 0, 0);
        }
    }
#pragma unroll
    for (int m = 0; m < 4; ++m) {
        int row = bm * BM + wr * 64 + m * 16 + lg * 4;
#pragma unroll
        for (int n = 0; n < 4; ++n) {
            int col = bn * BN + wc * 64 + n * 16 + lr;
            float bv = bias[col];
#pragma unroll
            for (int i = 0; i < 4; ++i) {
                Z[(size_t)(row + i) * N3 + col] = f2bf(acc[m][n][i] + bv);
            }
        }
    }
}

// ---------------------------------------------------------------- V transpose
__global__ __launch_bounds__(256) void transpose_v(
    const unsigned short* __restrict__ Z, unsigned short* __restrict__ Vt) {
    __shared__ unsigned short tile[64][72];
    int bid = blockIdx.x;
    int nh = bid >> 5;
    int cb = bid & 31;
    int n = nh >> 4, h = nh & 15;
    int t = threadIdx.x;
#pragma unroll
    for (int p = 0; p < 4; ++p) {
        int idx = p * 256 + t;
        int r = idx >> 4;
        int cg = idx & 15;
        u16x4 v = *reinterpret_cast<const u16x4*>(
            &Z[(size_t)(n * S_LEN + cb * 64 + r) * N3 + 2 * D_MODEL + h * HD + cg * 4]);
        *reinterpret_cast<u16x4*>(&tile[r][cg * 4]) = v;
    }
    __syncthreads();
#pragma unroll
    for (int p = 0; p < 4; ++p) {
        int idx = p * 256 + t;
        int d = idx >> 4;
        int cg = idx & 15;
        u16x4 o;
        o.x = tile[cg * 4 + 0][d];
        o.y = tile[cg * 4 + 1][d];
        o.z = tile[cg * 4 + 2][d];
        o.w = tile[cg * 4 + 3][d];
        *reinterpret_cast<u16x4*>(
            &Vt[((size_t)nh * 64 + d) * S_LEN + cb * 64 + cg * 4]) = o;
    }
}

// ---------------------------------------------------------------- flash attention
// Block = 4 waves, 128 q-rows (2 groups of 64), one head.  Wave w owns rows
// {g*64 + w*16 + lr} for g=0,1.  K/V double-buffered LDS (global_load_lds,
// source-XOR swizzle), exp2-domain online softmax, defer-max (THR=8 -> P<=256),
// 3 blocks/CU co-residency (full grid resident).
__global__ __launch_bounds__(256, 3) void attn(
    const unsigned short* __restrict__ Z, const unsigned short* __restrict__ Vt,
    float* __restrict__ Out) {
    const int ilin = blockIdx.y * 16 + blockIdx.x;          // grid (16, 32)
    const int head32 = (ilin & 7) * 4 + ((ilin >> 3) & 3);  // 4 heads per XCD
    const int qb = 15 - (ilin >> 5);                        // heavy-first
    const int n = head32 >> 4, h = head32 & 15;

    __shared__ unsigned short Kt[2][64 * 64];
    __shared__ unsigned short Vs[2][64 * 64];
    __shared__ unsigned short p_lds[4][32][72];

    const int t = threadIdx.x;
    const int lane = t & 63, w = t >> 6;
    const int lr = lane & 15, lg = lane >> 4;
    const int srow = lane >> 3, sslot = lane & 7;

    // Q fragments, 2 groups
    bf16x8 qf[2][2];
#pragma unroll
    for (int g = 0; g < 2; ++g) {
        const size_t zrowQ =
            (size_t)(n * S_LEN + qb * 128 + g * 64 + w * 16 + lr) * N3 + D_MODEL + h * HD;
        qf[g][0] = *reinterpret_cast<const bf16x8*>(&Z[zrowQ + lg * 8]);
        qf[g][1] = *reinterpret_cast<const bf16x8*>(&Z[zrowQ + 32 + lg * 8]);
    }

    auto STAGE = [&](int buf, int kb) {
#pragma unroll
        for (int p = 0; p < 2; ++p) {
            int rb = w * 16 + p * 8;
            int row = rb + srow;
            int seg = sslot ^ (row & 7);
            GLOAD_LDS(&Z[(size_t)(n * S_LEN + kb * 64 + row) * N3 + h * HD + seg * 8],
                      &Kt[buf][rb * 64]);
            GLOAD_LDS(&Vt[((size_t)head32 * 64 + row) * S_LEN + kb * 64 + seg * 8],
                      &Vs[buf][rb * 64]);
        }
    };

    f32x4 o[2][4] = {};
    float mrun[2][4], lrun[2][4];
#pragma unroll
    for (int g = 0; g < 2; ++g)
#pragma unroll
        for (int i = 0; i < 4; ++i) { mrun[g][i] = -1e30f; lrun[g][i] = 0.f; }

    const float SCL = 0.03125f * 1.44269504f;   // 1/sqrt(1024) * log2(e)
    const int nkb = 2 * qb + 2;

    STAGE(0, 0);
    int cur = 0;
    for (int kb = 0; kb < nkb; ++kb) {
        __syncthreads();
        if (kb + 1 < nkb) STAGE(cur ^ 1, kb + 1);
        const unsigned short* Kc = &Kt[cur][0];
        const unsigned short* Vc = &Vs[cur][0];

        // hoisted K fragments (shared by both groups)
        bf16x8 kf0[4], kf1[4];
#pragma unroll
        for (int cf = 0; cf < 4; ++cf) {
            int row = cf * 16 + lr;
            kf0[cf] = *reinterpret_cast<const bf16x8*>(
                &Kc[row * 64 + ((lg) ^ (row & 7)) * 8]);
            kf1[cf] = *reinterpret_cast<const bf16x8*>(
                &Kc[row * 64 + ((lg + 4) ^ (row & 7)) * 8]);
        }

#pragma unroll
        for (int g = 0; g < 2; ++g) {
            if (kb > 2 * qb + g) continue;   // group not yet in causal range
            // ---- S = Q K^T
            f32x4 s[4];
            __builtin_amdgcn_s_setprio(1);
#pragma unroll
            for (int cf = 0; cf < 4; ++cf) {
                f32x4 a = {};
                a = __builtin_amdgcn_mfma_f32_16x16x32_bf16(qf[g][0], kf0[cf], a, 0, 0, 0);
                a = __builtin_amdgcn_mfma_f32_16x16x32_bf16(qf[g][1], kf1[cf], a, 0, 0, 0);
                s[cf] = a;
            }
            __builtin_amdgcn_s_setprio(0);
            // ---- scale (log2 domain) + causal mask on diag tile
            const bool diag = (kb == 2 * qb + g);
#pragma unroll
            for (int cf = 0; cf < 4; ++cf) {
                int krel = cf * 16 + lr;
#pragma unroll
                for (int i = 0; i < 4; ++i) {
                    float v = s[cf][i] * SCL;
                    if (diag && krel > w * 16 + lg * 4 + i) v = -1e30f;
                    s[cf][i] = v;
                }
            }
            // ---- row max (per 16-lane group) + defer-max vote
            float pm[4];
#pragma unroll
            for (int i = 0; i < 4; ++i) {
                float v = fmaxf(fmaxf(s[0][i], s[1][i]), fmaxf(s[2][i], s[3][i]));
                v = fmaxf(v, __shfl_xor(v, 1));
                v = fmaxf(v, __shfl_xor(v, 2));
                v = fmaxf(v, __shfl_xor(v, 4));
                v = fmaxf(v, __shfl_xor(v, 8));
                pm[i] = v;
            }
            float worst = fmaxf(fmaxf(pm[0] - mrun[g][0], pm[1] - mrun[g][1]),
                                fmaxf(pm[2] - mrun[g][2], pm[3] - mrun[g][3]));
            if (!__all(worst <= 8.0f)) {
#pragma unroll
                for (int i = 0; i < 4; ++i) {
                    float mn = fmaxf(mrun[g][i], pm[i]);
                    float corr = exp2f(mrun[g][i] - mn);
                    mrun[g][i] = mn;
                    lrun[g][i] *= corr;
#pragma unroll
                    for (int cfd = 0; cfd < 4; ++cfd) o[g][cfd][i] *= corr;
                }
            }
            // ---- P = exp2(s - m), row-sum, store to per-wave LDS
#pragma unroll
            for (int i = 0; i < 4; ++i) {
                float sum = 0.f;
#pragma unroll
                for (int cf = 0; cf < 4; ++cf) {
                    float p = exp2f(s[cf][i] - mrun[g][i]);
                    s[cf][i] = p;
                    sum += p;
                }
                sum += __shfl_xor(sum, 1);
                sum += __shfl_xor(sum, 2);
                sum += __shfl_xor(sum, 4);
                sum += __shfl_xor(sum, 8);
                lrun[g][i] += sum;
            }
#pragma unroll
            for (int cf = 0; cf < 4; ++cf)
#pragma unroll
                for (int i = 0; i < 4; ++i)
                    p_lds[w][g * 16 + lg * 4 + i][cf * 16 + lr] = f2bf(s[cf][i]);
            // ---- O += P * V
            __builtin_amdgcn_s_setprio(1);
#pragma unroll
            for (int ks = 0; ks < 2; ++ks) {
                bf16x8 pf = *reinterpret_cast<const bf16x8*>(
                    &p_lds[w][g * 16 + lr][ks * 32 + lg * 8]);
#pragma unroll
                for (int cfd = 0; cfd < 4; ++cfd) {
                    int vrow = cfd * 16 + lr;
                    bf16x8 vf = *reinterpret_cast<const bf16x8*>(
                        &Vc[vrow * 64 + ((ks * 4 + lg) ^ (vrow & 7)) * 8]);
                    o[g][cfd] = __builtin_amdgcn_mfma_f32_16x16x32_bf16(
                        pf, vf, o[g][cfd], 0, 0, 0);
                }
            }
            __builtin_amdgcn_s_setprio(0);
        }
        cur ^= 1;
    }
    // ---- epilogue
#pragma unroll
    for (int g = 0; g < 2; ++g)
#pragma unroll
        for (int cfd = 0; cfd < 4; ++cfd) {
            int d = h * HD + cfd * 16 + lr;
#pragma unroll
            for (int i = 0; i < 4; ++i) {
                int q = qb * 128 + g * 64 + w * 16 + lg * 4 + i;
                Out[(size_t)(n * S_LEN + q) * D_MODEL + d] = o[g][cfd][i] / lrun[g][i];
            }
        }
}

// ----------------------------------------------------------------
extern "C" void kernel_launch(void* const* d_in, const int* in_sizes, int n_in,
                              void* d_out, int out_size, void* d_ws, size_t ws_size,
                              hipStream_t stream) {
    const float* x = (const float*)d_in[0];
    const float* W = (const float*)d_in[1];
    const float* b = (const float*)d_in[2];
    float* out = (float*)d_out;

    char* ws = (char*)d_ws;
    unsigned short* xb = (unsigned short*)ws;                                  // 8 MB
    unsigned short* Wb = (unsigned short*)(ws + (size_t)8 * 1024 * 1024);      // 6 MB
    unsigned short* Z  = (unsigned short*)(ws + (size_t)14 * 1024 * 1024);     // 24 MB
    unsigned short* Vt = (unsigned short*)(ws + (size_t)38 * 1024 * 1024);     // 8 MB

    cast_both<<<7168, 256, 0, stream>>>(x, W, xb, Wb);
    qkv_gemm<<<dim3(N3 / BN, M_TOT / BM), 256, 0, stream>>>(xb, Wb, b, Z);
    transpose_v<<<1024, 256, 0, stream>>>(Z, Vt);
    attn<<<dim3(16, 32), 256, 0, stream>>>(Z, Vt, out);
}

// Round 5
// 173.262 us; speedup vs baseline: 1.2793x; 1.2793x over previous
//
#include <hip/hip_runtime.h>
#include <hip/hip_bf16.h>

#define D_MODEL 1024
#define NH 16
#define HD 64
#define S_LEN 2048
#define NB 2
#define M_TOT 4096
#define N3 3072

typedef __attribute__((ext_vector_type(8))) short bf16x8;
typedef __attribute__((ext_vector_type(4))) float f32x4;
typedef __attribute__((ext_vector_type(4))) unsigned short u16x4;

__device__ __forceinline__ unsigned short f2bf(float f) {
    unsigned int u = __float_as_uint(f);
    u += 0x7fffu + ((u >> 16) & 1u);
    return (unsigned short)(u >> 16);
}
__device__ __forceinline__ float bf2f(unsigned short s) {
    return __uint_as_float((unsigned int)s << 16);
}

#define GLOAD_LDS(gp, lp)                                                      \
    __builtin_amdgcn_global_load_lds(                                          \
        (const __attribute__((address_space(1))) void*)(gp),                   \
        (__attribute__((address_space(3))) void*)(lp), 16, 0, 0)

// ---------------------------------------------------------------- fused casts
__global__ __launch_bounds__(256) void cast_both(
    const float* __restrict__ x, const float* __restrict__ W,
    unsigned short* __restrict__ xb, unsigned short* __restrict__ Wb) {
    const int nx = M_TOT * D_MODEL / 4;
    const int nw = N3 * D_MODEL / 4;
    int i = blockIdx.x * 256 + threadIdx.x;
    const float* src;
    unsigned short* dst;
    int j;
    if (i < nx) { src = x; dst = xb; j = i; }
    else { j = i - nx; if (j >= nw) return; src = W; dst = Wb; }
    float4 v = reinterpret_cast<const float4*>(src)[j];
    u16x4 o;
    o.x = f2bf(v.x); o.y = f2bf(v.y); o.z = f2bf(v.z); o.w = f2bf(v.w);
    reinterpret_cast<u16x4*>(dst)[j] = o;
}

// ---------------------------------------------------------------- QKV GEMM (m97 structure, unchanged)
#define BM 128
#define BN 128
#define BK 64

__global__ __launch_bounds__(256) void qkv_gemm(
    const unsigned short* __restrict__ A, const unsigned short* __restrict__ B,
    const float* __restrict__ bias, unsigned short* __restrict__ Z) {
    __shared__ unsigned short As[BM * BK];
    __shared__ unsigned short Bs[BN * BK];

    const int t = threadIdx.x;
    const int lane = t & 63;
    const int wid = t >> 6;
    const int wr = wid >> 1, wc = wid & 1;
    const int bm = blockIdx.y, bn = blockIdx.x;
    const int lr = lane & 15;
    const int lg = lane >> 4;
    const int srow = lane >> 3;
    const int sslot = lane & 7;

    f32x4 acc[4][4] = {};

    for (int k0 = 0; k0 < 1024; k0 += BK) {
        __syncthreads();
#pragma unroll
        for (int p = 0; p < 4; ++p) {
            int rb = wid * 32 + p * 8;
            int row = rb + srow;
            int seg = sslot ^ (row & 7);
            GLOAD_LDS(&A[(size_t)(bm * BM + row) * 1024 + k0 + seg * 8],
                      &As[rb * BK]);
            GLOAD_LDS(&B[(size_t)(bn * BN + row) * 1024 + k0 + seg * 8],
                      &Bs[rb * BK]);
        }
        __syncthreads();
#pragma unroll
        for (int ks = 0; ks < 2; ++ks) {
            bf16x8 af[4], bfr[4];
#pragma unroll
            for (int m = 0; m < 4; ++m) {
                int row = wr * 64 + m * 16 + lr;
                int slot = (ks * 4 + lg) ^ (row & 7);
                af[m] = *reinterpret_cast<const bf16x8*>(&As[row * BK + slot * 8]);
            }
#pragma unroll
            for (int n = 0; n < 4; ++n) {
                int row = wc * 64 + n * 16 + lr;
                int slot = (ks * 4 + lg) ^ (row & 7);
                bfr[n] = *reinterpret_cast<const bf16x8*>(&Bs[row * BK + slot * 8]);
            }
#pragma unroll
            for (int m = 0; m < 4; ++m)
#pragma unroll
                for (int n = 0; n < 4; ++n)
                    acc[m][n] = __builtin_amdgcn_mfma_f32_16x16x32_bf16(
                        af[m], bfr[n], acc[m][n], 0, 0, 0);
        }
    }
#pragma unroll
    for (int m = 0; m < 4; ++m) {
        int row = bm * BM + wr * 64 + m * 16 + lg * 4;
#pragma unroll
        for (int n = 0; n < 4; ++n) {
            int col = bn * BN + wc * 64 + n * 16 + lr;
            float bv = bias[col];
#pragma unroll
            for (int i = 0; i < 4; ++i) {
                Z[(size_t)(row + i) * N3 + col] = f2bf(acc[m][n][i] + bv);
            }
        }
    }
}

// ---------------------------------------------------------------- V transpose
__global__ __launch_bounds__(256) void transpose_v(
    const unsigned short* __restrict__ Z, unsigned short* __restrict__ Vt) {
    __shared__ unsigned short tile[64][72];
    int bid = blockIdx.x;
    int nh = bid >> 5;
    int cb = bid & 31;
    int n = nh >> 4, h = nh & 15;
    int t = threadIdx.x;
#pragma unroll
    for (int p = 0; p < 4; ++p) {
        int idx = p * 256 + t;
        int r = idx >> 4;
        int cg = idx & 15;
        u16x4 v = *reinterpret_cast<const u16x4*>(
            &Z[(size_t)(n * S_LEN + cb * 64 + r) * N3 + 2 * D_MODEL + h * HD + cg * 4]);
        *reinterpret_cast<u16x4*>(&tile[r][cg * 4]) = v;
    }
    __syncthreads();
#pragma unroll
    for (int p = 0; p < 4; ++p) {
        int idx = p * 256 + t;
        int d = idx >> 4;
        int cg = idx & 15;
        u16x4 o;
        o.x = tile[cg * 4 + 0][d];
        o.y = tile[cg * 4 + 1][d];
        o.z = tile[cg * 4 + 2][d];
        o.w = tile[cg * 4 + 3][d];
        *reinterpret_cast<u16x4*>(
            &Vt[((size_t)nh * 64 + d) * S_LEN + cb * 64 + cg * 4]) = o;
    }
}

// ---------------------------------------------------------------- flash attention
// Round-3 structure (64 q-rows/block, 1024 blocks, dbuf LDS K/V) + swapped
// QK^T: S computed as mfma(K,Q) so D gives lane -> one q-row (q = lane&15),
// 16 key-scores in-lane.  Softmax = in-lane tree + 2 shfl_xor.  m/l are
// per-lane scalars; rescale corr broadcast via 4 shfl only when defer-max
// (THR=8, log2 domain) triggers.
__global__ __launch_bounds__(256) void attn(
    const unsigned short* __restrict__ Z, const unsigned short* __restrict__ Vt,
    float* __restrict__ Out) {
    const int ilin = blockIdx.y * 32 + blockIdx.x;
    const int head32 = (ilin & 7) * 4 + ((ilin >> 3) & 3);   // 4 heads per XCD
    const int qb = 31 - (ilin >> 5);                          // heavy-first
    const int n = head32 >> 4, h = head32 & 15;

    __shared__ unsigned short Kt[2][64 * 64];
    __shared__ unsigned short Vs[2][64 * 64];
    __shared__ unsigned short p_lds[4][16][72];

    const int t = threadIdx.x;
    const int lane = t & 63, w = t >> 6;
    const int lr = lane & 15, lg = lane >> 4;
    const int srow = lane >> 3, sslot = lane & 7;

    const float SCL = 0.03125f * 1.44269504f;   // 1/sqrt(1024) * log2(e)

    // Q fragment (B-operand for swapped QK: col=lane&15=q, k=(lane>>4)*8+j)
    // pre-scaled by SCL so S comes out of MFMA already in log2-exp domain.
    const size_t zrowQ = (size_t)(n * S_LEN + qb * 64 + w * 16 + lr) * N3 + D_MODEL + h * HD;
    bf16x8 qf[2];
#pragma unroll
    for (int f = 0; f < 2; ++f) {
        bf16x8 raw = *reinterpret_cast<const bf16x8*>(&Z[zrowQ + f * 32 + lg * 8]);
        bf16x8 sc;
#pragma unroll
        for (int j = 0; j < 8; ++j)
            sc[j] = (short)f2bf(bf2f((unsigned short)raw[j]) * SCL);
        qf[f] = sc;
    }

    auto STAGE = [&](int buf, int kb) {
#pragma unroll
        for (int p = 0; p < 2; ++p) {
            int rb = w * 16 + p * 8;
            int row = rb + srow;
            int seg = sslot ^ (row & 7);
            GLOAD_LDS(&Z[(size_t)(n * S_LEN + kb * 64 + row) * N3 + h * HD + seg * 8],
                      &Kt[buf][rb * 64]);
            GLOAD_LDS(&Vt[((size_t)head32 * 64 + row) * S_LEN + kb * 64 + seg * 8],
                      &Vs[buf][rb * 64]);
        }
    };

    f32x4 o[4] = {};
    float mrun = -1e30f, lrun = 0.f;   // per-lane: q-row = lane&15

    STAGE(0, 0);
    int cur = 0;
    for (int kb = 0; kb <= qb; ++kb) {
        __syncthreads();
        if (kb < qb) STAGE(cur ^ 1, kb + 1);
        const unsigned short* Kc = &Kt[cur][0];
        const unsigned short* Vc = &Vs[cur][0];

        // ---- S^T = K Q^T : lane holds s[cf][i] = S[key=cf*16+lg*4+i][q=lr]
        f32x4 s[4];
        __builtin_amdgcn_s_setprio(1);
#pragma unroll
        for (int cf = 0; cf < 4; ++cf) {
            int row = cf * 16 + lr;
            bf16x8 kf0 = *reinterpret_cast<const bf16x8*>(
                &Kc[row * 64 + ((lg) ^ (row & 7)) * 8]);
            bf16x8 kf1 = *reinterpret_cast<const bf16x8*>(
                &Kc[row * 64 + ((lg + 4) ^ (row & 7)) * 8]);
            f32x4 a = {};
            a = __builtin_amdgcn_mfma_f32_16x16x32_bf16(kf0, qf[0], a, 0, 0, 0);
            a = __builtin_amdgcn_mfma_f32_16x16x32_bf16(kf1, qf[1], a, 0, 0, 0);
            s[cf] = a;
        }
        __builtin_amdgcn_s_setprio(0);

        // ---- causal mask (diag tile only); scores already scaled (Q pre-scale)
        if (kb == qb) {
            const int qloc = w * 16 + lr;
#pragma unroll
            for (int cf = 0; cf < 4; ++cf) {
                int kbase = cf * 16 + lg * 4;
#pragma unroll
                for (int i = 0; i < 4; ++i)
                    if (kbase + i > qloc) s[cf][i] = -1e30f;
            }
        }

        // ---- in-lane row max + 2-shfl reduce (across the 4 lg copies of q)
        float pm;
        {
            f32x4 m4 = s[0];
#pragma unroll
            for (int cf = 1; cf < 4; ++cf) {
                m4[0] = fmaxf(m4[0], s[cf][0]); m4[1] = fmaxf(m4[1], s[cf][1]);
                m4[2] = fmaxf(m4[2], s[cf][2]); m4[3] = fmaxf(m4[3], s[cf][3]);
            }
            pm = fmaxf(fmaxf(m4[0], m4[1]), fmaxf(m4[2], m4[3]));
            pm = fmaxf(pm, __shfl_xor(pm, 16));
            pm = fmaxf(pm, __shfl_xor(pm, 32));
        }
        // ---- defer-max rescale
        if (!__all(pm - mrun <= 8.0f)) {
            float mn = fmaxf(mrun, pm);
            float corr = exp2f(mrun - mn);
            mrun = mn;
            lrun *= corr;
#pragma unroll
            for (int i = 0; i < 4; ++i) {
                float ci = __shfl(corr, lg * 4 + i);   // corr for q = lg*4+i
#pragma unroll
                for (int cfd = 0; cfd < 4; ++cfd) o[cfd][i] *= ci;
            }
        }
        // ---- P = exp2(s - m) in-lane; sum; pack pairs -> per-wave LDS
        float sum = 0.f;
#pragma unroll
        for (int cf = 0; cf < 4; ++cf) {
#pragma unroll
            for (int i = 0; i < 4; ++i) {
                float p = exp2f(s[cf][i] - mrun);
                s[cf][i] = p;
                sum += p;
            }
            unsigned int lo01 = (unsigned int)f2bf(s[cf][0]) |
                                ((unsigned int)f2bf(s[cf][1]) << 16);
            unsigned int lo23 = (unsigned int)f2bf(s[cf][2]) |
                                ((unsigned int)f2bf(s[cf][3]) << 16);
            *reinterpret_cast<unsigned int*>(&p_lds[w][lr][cf * 16 + lg * 4]) = lo01;
            *reinterpret_cast<unsigned int*>(&p_lds[w][lr][cf * 16 + lg * 4 + 2]) = lo23;
        }
        sum += __shfl_xor(sum, 16);
        sum += __shfl_xor(sum, 32);
        lrun += sum;

        // ---- O += P * V
        __builtin_amdgcn_s_setprio(1);
#pragma unroll
        for (int ks = 0; ks < 2; ++ks) {
            bf16x8 pf = *reinterpret_cast<const bf16x8*>(&p_lds[w][lr][ks * 32 + lg * 8]);
#pragma unroll
            for (int cfd = 0; cfd < 4; ++cfd) {
                int vrow = cfd * 16 + lr;
                bf16x8 vf = *reinterpret_cast<const bf16x8*>(
                    &Vc[vrow * 64 + ((ks * 4 + lg) ^ (vrow & 7)) * 8]);
                o[cfd] = __builtin_amdgcn_mfma_f32_16x16x32_bf16(pf, vf, o[cfd], 0, 0, 0);
            }
        }
        __builtin_amdgcn_s_setprio(0);
        cur ^= 1;
    }
    // ---- epilogue: out = O / l   (l lives at lane q=lr; o rows are q=lg*4+i)
#pragma unroll
    for (int i = 0; i < 4; ++i) {
        float li = __shfl(lrun, lg * 4 + i);
        float inv = 1.0f / li;
        int q = qb * 64 + w * 16 + lg * 4 + i;
#pragma unroll
        for (int cfd = 0; cfd < 4; ++cfd) {
            int d = h * HD + cfd * 16 + lr;
            Out[(size_t)(n * S_LEN + q) * D_MODEL + d] = o[cfd][i] * inv;
        }
    }
}

// ----------------------------------------------------------------
extern "C" void kernel_launch(void* const* d_in, const int* in_sizes, int n_in,
                              void* d_out, int out_size, void* d_ws, size_t ws_size,
                              hipStream_t stream) {
    const float* x = (const float*)d_in[0];
    const float* W = (const float*)d_in[1];
    const float* b = (const float*)d_in[2];
    float* out = (float*)d_out;

    char* ws = (char*)d_ws;
    unsigned short* xb = (unsigned short*)ws;                                  // 8 MB
    unsigned short* Wb = (unsigned short*)(ws + (size_t)8 * 1024 * 1024);      // 6 MB
    unsigned short* Z  = (unsigned short*)(ws + (size_t)14 * 1024 * 1024);     // 24 MB
    unsigned short* Vt = (unsigned short*)(ws + (size_t)38 * 1024 * 1024);     // 8 MB

    cast_both<<<7168, 256, 0, stream>>>(x, W, xb, Wb);
    qkv_gemm<<<dim3(N3 / BN, M_TOT / BM), 256, 0, stream>>>(xb, Wb, b, Z);
    transpose_v<<<1024, 256, 0, stream>>>(Z, Vt);
    attn<<<dim3(32, 32), 256, 0, stream>>>(Z, Vt, out);
}